// Round 1
// baseline (544.875 us; speedup 1.0000x reference)
//
#include <hip/hip_runtime.h>
#include <hip/hip_bf16.h>

#define N_NODES 50000
#define N_EDGES 500000
#define E_AUG   (N_EDGES + N_NODES)   // 550000
#define NH1 4
#define HID 64
#define C1  256                        // NH1*HID
#define C2  64

// ---------------- CSR build ----------------

__global__ void deg_loop_kernel(const int* __restrict__ ei, const float* __restrict__ ea,
                                int* __restrict__ deg, float* __restrict__ lsum) {
    int e = blockIdx.x * 256 + threadIdx.x;
    if (e >= N_EDGES) return;
    int d = ei[N_EDGES + e];
    atomicAdd(&deg[d], 1);
    atomicAdd(&lsum[2 * d + 0], ea[2 * e + 0]);
    atomicAdd(&lsum[2 * d + 1], ea[2 * e + 1]);
}

__global__ void scan1_kernel(const int* __restrict__ deg, int* __restrict__ offs,
                             int* __restrict__ bsum) {
    __shared__ int s[256];
    int tid = threadIdx.x;
    int i = blockIdx.x * 256 + tid;
    int v = (i < N_NODES) ? (deg[i] + 1) : 0;   // +1 self loop
    s[tid] = v;
    __syncthreads();
    for (int off = 1; off < 256; off <<= 1) {
        int t = (tid >= off) ? s[tid - off] : 0;
        __syncthreads();
        s[tid] += t;
        __syncthreads();
    }
    if (i < N_NODES) offs[i + 1] = s[tid];
    if (tid == 255) bsum[blockIdx.x] = s[255];
}

__global__ void scan2_kernel(int* __restrict__ bsum, int nb) {
    __shared__ int s[256];
    int tid = threadIdx.x;
    int v = (tid < nb) ? bsum[tid] : 0;
    s[tid] = v;
    __syncthreads();
    for (int off = 1; off < 256; off <<= 1) {
        int t = (tid >= off) ? s[tid - off] : 0;
        __syncthreads();
        s[tid] += t;
        __syncthreads();
    }
    if (tid < nb) bsum[tid] = s[tid] - v;   // exclusive
}

__global__ void scan3_kernel(int* __restrict__ offs, const int* __restrict__ bsum) {
    int i = blockIdx.x * 256 + threadIdx.x;
    if (i < N_NODES) offs[i + 1] += bsum[i >> 8];
    if (i == 0) offs[0] = 0;
}

__global__ void scatter_kernel(const int* __restrict__ ei, const float* __restrict__ ea,
                               const int* __restrict__ deg, const float* __restrict__ lsum,
                               const int* __restrict__ offs, int* __restrict__ cnt,
                               int* __restrict__ e_src, float* __restrict__ e_ea) {
    int e = blockIdx.x * 256 + threadIdx.x;
    if (e >= E_AUG) return;
    int s, d; float a0, a1;
    if (e < N_EDGES) {
        s = ei[e]; d = ei[N_EDGES + e];
        a0 = ea[2 * e + 0]; a1 = ea[2 * e + 1];
    } else {
        int n = e - N_EDGES;
        s = n; d = n;
        float dg = (float)max(deg[n], 1);
        a0 = lsum[2 * n + 0] / dg;
        a1 = lsum[2 * n + 1] / dg;
    }
    int pos = offs[d] + atomicAdd(&cnt[d], 1);
    e_src[pos] = s;
    e_ea[2 * pos + 0] = a0;
    e_ea[2 * pos + 1] = a1;
}

// ---------------- Layer 1: fused GATv2 (K=2, H=4, C=64) ----------------

__global__ __launch_bounds__(256) void l1_node_kernel(
    const float* __restrict__ x, const int* __restrict__ offs,
    const int* __restrict__ e_src, const float* __restrict__ e_ea,
    const float* __restrict__ W1l, const float* __restrict__ b1l,
    const float* __restrict__ W1r, const float* __restrict__ b1r,
    const float* __restrict__ W1e, const float* __restrict__ att1,
    const float* __restrict__ bias1,
    float* __restrict__ alpha1, float* __restrict__ hout) {
    __shared__ float sWl[512], sWr[512], sWe[512];
    __shared__ float sbl[256], sbr[256], satt[256], sbias[256];
    int tid = threadIdx.x;
    for (int i = tid; i < 512; i += 256) { sWl[i] = W1l[i]; sWr[i] = W1r[i]; sWe[i] = W1e[i]; }
    sbl[tid] = b1l[tid]; sbr[tid] = b1r[tid]; satt[tid] = att1[tid]; sbias[tid] = bias1[tid];
    __syncthreads();

    int l = tid & 63;
    int n = blockIdx.x * 4 + (tid >> 6);

    const float2 xn = *(const float2*)&x[2 * n];
    float xr[NH1];
    #pragma unroll
    for (int h = 0; h < NH1; ++h) {
        int c = h * 64 + l;
        xr[h] = xn.x * sWr[c] + xn.y * sWr[256 + c] + sbr[c];
    }

    int beg = offs[n], end = offs[n + 1];
    float amax[NH1] = {-1e30f, -1e30f, -1e30f, -1e30f};

    for (int e = beg; e < end; ++e) {
        int s = e_src[e];
        const float2 aev = *(const float2*)&e_ea[2 * e];
        const float2 xs = *(const float2*)&x[2 * s];
        float p[NH1];
        #pragma unroll
        for (int h = 0; h < NH1; ++h) {
            int c = h * 64 + l;
            float xl = xs.x * sWl[c] + xs.y * sWl[256 + c] + sbl[c];
            float ee = aev.x * sWe[c] + aev.y * sWe[256 + c];
            float t = xl + xr[h] + ee;
            t = t > 0.0f ? t : 0.2f * t;
            p[h] = t * satt[c];
        }
        #pragma unroll
        for (int off = 32; off; off >>= 1) {
            #pragma unroll
            for (int h = 0; h < NH1; ++h) p[h] += __shfl_xor(p[h], off);
        }
        #pragma unroll
        for (int h = 0; h < NH1; ++h) amax[h] = fmaxf(amax[h], p[h]);
        if (l == 0) {
            float4 v = make_float4(p[0], p[1], p[2], p[3]);
            *(float4*)&alpha1[4 * e] = v;
        }
    }

    float acc[NH1] = {0, 0, 0, 0};
    float den[NH1] = {0, 0, 0, 0};
    for (int e = beg; e < end; ++e) {
        int s = e_src[e];
        const float4 al4 = *(const float4*)&alpha1[4 * e];
        float alv[4] = {al4.x, al4.y, al4.z, al4.w};
        const float2 xs = *(const float2*)&x[2 * s];
        #pragma unroll
        for (int h = 0; h < NH1; ++h) {
            float ex = expf(alv[h] - amax[h]);
            den[h] += ex;
            int c = h * 64 + l;
            float xl = xs.x * sWl[c] + xs.y * sWl[256 + c] + sbl[c];
            acc[h] += ex * xl;
        }
    }

    #pragma unroll
    for (int h = 0; h < NH1; ++h) {
        int c = h * 64 + l;
        float v = acc[h] / (den[h] + 1e-16f) + sbias[c];
        v = v > 0.0f ? v : expm1f(v);       // ELU
        hout[n * C1 + c] = v;
    }
}

// ---------------- Layer 2 projections: h[N,256] @ W[256,64] (x2) ----------------

__global__ __launch_bounds__(256) void gemm2_kernel(
    const float* __restrict__ hmat,
    const float* __restrict__ Wl, const float* __restrict__ bl,
    const float* __restrict__ Wr, const float* __restrict__ br,
    float* __restrict__ xl2, float* __restrict__ xr2) {
    __shared__ float hs[16 * 256];
    const int tid = threadIdx.x;
    const int n0 = blockIdx.x * 16;
    for (int i = tid; i < 16 * 256; i += 256) hs[i] = hmat[n0 * 256 + i];
    const float* W = blockIdx.y ? Wr : Wl;
    const float* bias = blockIdx.y ? br : bl;
    float* out = blockIdx.y ? xr2 : xl2;
    __syncthreads();
    const int c = tid & 63, q = tid >> 6;
    float acc[4] = {0, 0, 0, 0};
    for (int k = 0; k < 256; k += 4) {
        float w0 = W[(k + 0) * 64 + c];
        float w1 = W[(k + 1) * 64 + c];
        float w2 = W[(k + 2) * 64 + c];
        float w3 = W[(k + 3) * 64 + c];
        #pragma unroll
        for (int j = 0; j < 4; ++j) {
            const float4 hv = *(const float4*)&hs[(q * 4 + j) * 256 + k];
            acc[j] += hv.x * w0 + hv.y * w1 + hv.z * w2 + hv.w * w3;
        }
    }
    #pragma unroll
    for (int j = 0; j < 4; ++j)
        out[(n0 + q * 4 + j) * 64 + c] = acc[j] + bias[c];
}

// ---------------- Layer 2: fused GATv2 (C=64, H=1) ----------------

__global__ __launch_bounds__(256) void l2_node_kernel(
    const float* __restrict__ xl2, const float* __restrict__ xr2,
    const int* __restrict__ offs, const int* __restrict__ e_src,
    const float* __restrict__ e_ea,
    const float* __restrict__ W2e, const float* __restrict__ att2,
    const float* __restrict__ bias2,
    float* __restrict__ alpha2, float* __restrict__ out2) {
    __shared__ float sWe[128], satt[64], sb[64];
    int tid = threadIdx.x;
    if (tid < 128) sWe[tid] = W2e[tid];
    if (tid < 64) { satt[tid] = att2[tid]; sb[tid] = bias2[tid]; }
    __syncthreads();

    int l = tid & 63;
    int n = blockIdx.x * 4 + (tid >> 6);

    float xr = xr2[n * C2 + l];
    int beg = offs[n], end = offs[n + 1];
    float amax = -1e30f;

    for (int e = beg; e < end; ++e) {
        int s = e_src[e];
        const float2 aev = *(const float2*)&e_ea[2 * e];
        float xl = xl2[s * C2 + l];
        float ee = aev.x * sWe[l] + aev.y * sWe[64 + l];
        float t = xl + xr + ee;
        t = t > 0.0f ? t : 0.2f * t;
        float p = t * satt[l];
        #pragma unroll
        for (int off = 32; off; off >>= 1) p += __shfl_xor(p, off);
        amax = fmaxf(amax, p);
        if (l == 0) alpha2[e] = p;
    }

    float acc = 0.0f, den = 0.0f;
    for (int e = beg; e < end; ++e) {
        int s = e_src[e];
        float ex = expf(alpha2[e] - amax);
        den += ex;
        acc += ex * xl2[s * C2 + l];
    }
    out2[n * C2 + l] = acc / (den + 1e-16f) + sb[l];
}

// ---------------- Mean pool ----------------

__global__ __launch_bounds__(256) void pool_kernel(const float* __restrict__ out2,
                                                   float* __restrict__ d_out) {
    __shared__ float s[256];
    int tid = threadIdx.x;
    float local = 0.0f;
    for (long long i = (long long)blockIdx.x * 256 + tid; i < (long long)N_NODES * C2;
         i += (long long)gridDim.x * 256)
        local += out2[i];
    s[tid] = local;
    __syncthreads();
    if (tid < 64) {
        float v = s[tid] + s[tid + 64] + s[tid + 128] + s[tid + 192];
        atomicAdd(&d_out[tid], v * (1.0f / N_NODES));
    }
}

// ---------------- Host launch ----------------

extern "C" void kernel_launch(void* const* d_in, const int* in_sizes, int n_in,
                              void* d_out, int out_size, void* d_ws, size_t ws_size,
                              hipStream_t stream) {
    const float* x     = (const float*)d_in[0];
    const float* eattr = (const float*)d_in[1];
    const float* W1l   = (const float*)d_in[2];
    const float* b1l   = (const float*)d_in[3];
    const float* W1r   = (const float*)d_in[4];
    const float* b1r   = (const float*)d_in[5];
    const float* W1e   = (const float*)d_in[6];
    const float* att1  = (const float*)d_in[7];
    const float* bias1 = (const float*)d_in[8];
    const float* W2l   = (const float*)d_in[9];
    const float* b2l   = (const float*)d_in[10];
    const float* W2r   = (const float*)d_in[11];
    const float* b2r   = (const float*)d_in[12];
    const float* W2e   = (const float*)d_in[13];
    const float* att2  = (const float*)d_in[14];
    const float* bias2 = (const float*)d_in[15];
    const int*   ei    = (const int*)d_in[16];
    float* out = (float*)d_out;

    // workspace layout (256B aligned blocks)
    char* p = (char*)d_ws;
    auto alloc = [&](size_t bytes) -> void* {
        void* r = (void*)p;
        p += (bytes + 255) & ~(size_t)255;
        return r;
    };
    int*   deg    = (int*)alloc(N_NODES * 4);
    int*   cnt    = (int*)alloc(N_NODES * 4);
    int*   offs   = (int*)alloc((N_NODES + 1) * 4);
    float* lsum   = (float*)alloc(N_NODES * 2 * 4);
    int*   bsum   = (int*)alloc(256 * 4);
    int*   e_src  = (int*)alloc(E_AUG * 4);
    float* e_ea   = (float*)alloc(E_AUG * 2 * 4);
    float* alpha1 = (float*)alloc((size_t)E_AUG * 4 * 4);
    float* hbuf   = (float*)alloc((size_t)N_NODES * C1 * 4);
    float* xl2    = (float*)alloc((size_t)N_NODES * C2 * 4);
    float* xr2    = (float*)alloc((size_t)N_NODES * C2 * 4);
    float* out2   = (float*)alloc((size_t)N_NODES * C2 * 4);
    float* alpha2 = (float*)alloc((size_t)E_AUG * 4);

    hipMemsetAsync(deg, 0, N_NODES * 4, stream);
    hipMemsetAsync(cnt, 0, N_NODES * 4, stream);
    hipMemsetAsync(lsum, 0, N_NODES * 2 * 4, stream);
    hipMemsetAsync(d_out, 0, 64 * 4, stream);

    deg_loop_kernel<<<(N_EDGES + 255) / 256, 256, 0, stream>>>(ei, eattr, deg, lsum);
    int nb = (N_NODES + 255) / 256;   // 196
    scan1_kernel<<<nb, 256, 0, stream>>>(deg, offs, bsum);
    scan2_kernel<<<1, 256, 0, stream>>>(bsum, nb);
    scan3_kernel<<<nb, 256, 0, stream>>>(offs, bsum);
    scatter_kernel<<<(E_AUG + 255) / 256, 256, 0, stream>>>(ei, eattr, deg, lsum, offs, cnt,
                                                            e_src, e_ea);

    l1_node_kernel<<<N_NODES / 4, 256, 0, stream>>>(x, offs, e_src, e_ea,
                                                    W1l, b1l, W1r, b1r, W1e, att1, bias1,
                                                    alpha1, hbuf);

    gemm2_kernel<<<dim3(N_NODES / 16, 2), 256, 0, stream>>>(hbuf, W2l, b2l, W2r, b2r, xl2, xr2);

    l2_node_kernel<<<N_NODES / 4, 256, 0, stream>>>(xl2, xr2, offs, e_src, e_ea,
                                                    W2e, att2, bias2, alpha2, out2);

    pool_kernel<<<256, 256, 0, stream>>>(out2, out);
}

// Round 2
// 483.793 us; speedup vs baseline: 1.1263x; 1.1263x over previous
//
#include <hip/hip_runtime.h>
#include <hip/hip_bf16.h>

#define N_NODES 50000
#define N_EDGES 500000
#define E_AUG   (N_EDGES + N_NODES)   // 550000
#define NH1 4
#define HID 64
#define C1  256                        // NH1*HID
#define C2  64

// ---------------- weight packing ----------------
// Wpack[c][h][8] = {Wl0, Wl1, Wr0, Wr1, We0, We1, b1l+b1r, att1} for column hc=h*64+c
// W2lt/W2rt = W2 transposed to [64][256] so the GEMM loads float4 along k.

__global__ void pack_kernel(const float* __restrict__ W1l, const float* __restrict__ b1l,
                            const float* __restrict__ W1r, const float* __restrict__ b1r,
                            const float* __restrict__ W1e, const float* __restrict__ att1,
                            const float* __restrict__ W2l, const float* __restrict__ W2r,
                            float* __restrict__ Wpack, float* __restrict__ W2lt,
                            float* __restrict__ W2rt) {
    int t = blockIdx.x * 256 + threadIdx.x;
    if (t < 256) {
        int h = t >> 6, c = t & 63, hc = t;
        float* wp = &Wpack[(c * 4 + h) * 8];
        wp[0] = W1l[hc];       wp[1] = W1l[256 + hc];
        wp[2] = W1r[hc];       wp[3] = W1r[256 + hc];
        wp[4] = W1e[hc];       wp[5] = W1e[256 + hc];
        wp[6] = b1l[hc] + b1r[hc];
        wp[7] = att1[hc];
    }
    if (t < 64 * 256) {
        int c = t & 63, k = t >> 6;
        W2lt[c * 256 + k] = W2l[k * 64 + c];
        W2rt[c * 256 + k] = W2r[k * 64 + c];
    }
}

// ---------------- CSR build ----------------

__global__ void deg_loop_kernel(const int* __restrict__ ei, const float* __restrict__ ea,
                                int* __restrict__ deg, float* __restrict__ lsum) {
    int e = blockIdx.x * 256 + threadIdx.x;
    if (e >= N_EDGES) return;
    int d = ei[N_EDGES + e];
    atomicAdd(&deg[d], 1);
    atomicAdd(&lsum[2 * d + 0], ea[2 * e + 0]);
    atomicAdd(&lsum[2 * d + 1], ea[2 * e + 1]);
}

__global__ void scan1_kernel(const int* __restrict__ deg, int* __restrict__ offs,
                             int* __restrict__ bsum) {
    __shared__ int s[256];
    int tid = threadIdx.x;
    int i = blockIdx.x * 256 + tid;
    int v = (i < N_NODES) ? (deg[i] + 1) : 0;   // +1 self loop
    s[tid] = v;
    __syncthreads();
    for (int off = 1; off < 256; off <<= 1) {
        int t = (tid >= off) ? s[tid - off] : 0;
        __syncthreads();
        s[tid] += t;
        __syncthreads();
    }
    if (i < N_NODES) offs[i + 1] = s[tid];
    if (tid == 255) bsum[blockIdx.x] = s[255];
}

__global__ void scan2_kernel(int* __restrict__ bsum, int nb) {
    __shared__ int s[256];
    int tid = threadIdx.x;
    int v = (tid < nb) ? bsum[tid] : 0;
    s[tid] = v;
    __syncthreads();
    for (int off = 1; off < 256; off <<= 1) {
        int t = (tid >= off) ? s[tid - off] : 0;
        __syncthreads();
        s[tid] += t;
        __syncthreads();
    }
    if (tid < nb) bsum[tid] = s[tid] - v;   // exclusive
}

__global__ void scan3_kernel(int* __restrict__ offs, const int* __restrict__ bsum) {
    int i = blockIdx.x * 256 + threadIdx.x;
    if (i < N_NODES) offs[i + 1] += bsum[i >> 8];
    if (i == 0) offs[0] = 0;
}

__global__ void scatter_kernel(const int* __restrict__ ei, const float* __restrict__ ea,
                               const int* __restrict__ deg, const float* __restrict__ lsum,
                               const int* __restrict__ offs, int* __restrict__ cnt,
                               int* __restrict__ e_src, int* __restrict__ e_dst,
                               float* __restrict__ e_ea) {
    int e = blockIdx.x * 256 + threadIdx.x;
    if (e >= E_AUG) return;
    int s, d; float a0, a1;
    if (e < N_EDGES) {
        s = ei[e]; d = ei[N_EDGES + e];
        a0 = ea[2 * e + 0]; a1 = ea[2 * e + 1];
    } else {
        int n = e - N_EDGES;
        s = n; d = n;
        float dg = (float)max(deg[n], 1);
        a0 = lsum[2 * n + 0] / dg;
        a1 = lsum[2 * n + 1] / dg;
    }
    int pos = offs[d] + atomicAdd(&cnt[d], 1);
    e_src[pos] = s;
    e_dst[pos] = d;
    e_ea[2 * pos + 0] = a0;
    e_ea[2 * pos + 1] = a1;
}

// ---------------- Layer 1 alpha: edge-parallel, 4 edges/thread ----------------

__global__ __launch_bounds__(256) void l1_alpha_kernel(
    const float* __restrict__ x, const int* __restrict__ e_src,
    const int* __restrict__ e_dst, const float* __restrict__ e_ea,
    const float* __restrict__ Wpack, float* __restrict__ alpha1) {
    int e0 = (blockIdx.x * 256 + threadIdx.x) * 4;
    if (e0 >= E_AUG) return;
    int m = min(4, E_AUG - e0);

    float u0[4], u1[4], u2[4], u3[4], u4[4], u5[4];
    #pragma unroll
    for (int j = 0; j < 4; ++j) {
        int e = (j < m) ? (e0 + j) : e0;
        int s = e_src[e], d = e_dst[e];
        float2 xs = *(const float2*)&x[2 * s];
        float2 xd = *(const float2*)&x[2 * d];
        float2 ae = *(const float2*)&e_ea[2 * e];
        u0[j] = xs.x; u1[j] = xs.y; u2[j] = xd.x; u3[j] = xd.y; u4[j] = ae.x; u5[j] = ae.y;
    }

    float p[4][4];
    #pragma unroll
    for (int h = 0; h < 4; ++h)
        #pragma unroll
        for (int j = 0; j < 4; ++j) p[h][j] = 0.0f;

    for (int c = 0; c < 64; ++c) {
        const float* wp = &Wpack[c * 32];
        #pragma unroll
        for (int h = 0; h < 4; ++h) {
            float w0 = wp[h * 8 + 0], w1 = wp[h * 8 + 1], w2 = wp[h * 8 + 2],
                  w3 = wp[h * 8 + 3], w4 = wp[h * 8 + 4], w5 = wp[h * 8 + 5],
                  w6 = wp[h * 8 + 6], w7 = wp[h * 8 + 7];
            #pragma unroll
            for (int j = 0; j < 4; ++j) {
                float t = fmaf(u0[j], w0,
                          fmaf(u1[j], w1,
                          fmaf(u2[j], w2,
                          fmaf(u3[j], w3,
                          fmaf(u4[j], w4,
                          fmaf(u5[j], w5, w6))))));
                t = t > 0.0f ? t : 0.2f * t;
                p[h][j] = fmaf(t, w7, p[h][j]);
            }
        }
    }

    for (int j = 0; j < m; ++j) {
        float4 v = make_float4(p[0][j], p[1][j], p[2][j], p[3][j]);
        *(float4*)&alpha1[4 * (e0 + j)] = v;
    }
}

// ---------------- Layer 1 softmax + rank-2 weighted sums ----------------
// Sbuf[n][0..3] = sum_e w_eh * x[s_e].x ; Sbuf[n][4..7] = sum_e w_eh * x[s_e].y

__global__ __launch_bounds__(256) void l1_softmax_kernel(
    const float* __restrict__ x, const int* __restrict__ offs,
    const int* __restrict__ e_src, const float* __restrict__ alpha1,
    float* __restrict__ Sbuf) {
    int n = blockIdx.x * 256 + threadIdx.x;
    if (n >= N_NODES) return;
    int beg = offs[n], end = offs[n + 1];

    float amax[4] = {-1e30f, -1e30f, -1e30f, -1e30f};
    for (int e = beg; e < end; ++e) {
        const float4 lg = *(const float4*)&alpha1[4 * e];
        amax[0] = fmaxf(amax[0], lg.x); amax[1] = fmaxf(amax[1], lg.y);
        amax[2] = fmaxf(amax[2], lg.z); amax[3] = fmaxf(amax[3], lg.w);
    }
    float den[4] = {0, 0, 0, 0}, s1[4] = {0, 0, 0, 0}, s2[4] = {0, 0, 0, 0};
    for (int e = beg; e < end; ++e) {
        const float4 lg = *(const float4*)&alpha1[4 * e];
        float lgv[4] = {lg.x, lg.y, lg.z, lg.w};
        int s = e_src[e];
        float2 xs = *(const float2*)&x[2 * s];
        #pragma unroll
        for (int h = 0; h < 4; ++h) {
            float ex = __expf(lgv[h] - amax[h]);
            den[h] += ex;
            s1[h] = fmaf(ex, xs.x, s1[h]);
            s2[h] = fmaf(ex, xs.y, s2[h]);
        }
    }
    #pragma unroll
    for (int h = 0; h < 4; ++h) {
        float inv = 1.0f / (den[h] + 1e-16f);
        Sbuf[n * 8 + h] = s1[h] * inv;
        Sbuf[n * 8 + 4 + h] = s2[h] * inv;
    }
}

// ---------------- Layer 1 output tile (in LDS) + layer 2 projections ----------------
// h[n,hc] = elu(Wl0[hc]*S1[n,h] + Wl1[hc]*S2[n,h] + b1l[hc] + bias1[hc])  (never hits HBM)
// xl2 = h@W2l + b2l ; xr2 = h@W2r + b2r

__global__ __launch_bounds__(256) void l1out_gemm_kernel(
    const float* __restrict__ Sbuf,
    const float* __restrict__ W1l, const float* __restrict__ b1l,
    const float* __restrict__ bias1,
    const float* __restrict__ W2lt, const float* __restrict__ b2l,
    const float* __restrict__ W2rt, const float* __restrict__ b2r,
    float* __restrict__ xl2, float* __restrict__ xr2) {
    __shared__ float sS[16][8];
    __shared__ float hs[16][256];
    const int tid = threadIdx.x;
    const int n0 = blockIdx.x * 16;
    if (tid < 128) sS[tid >> 3][tid & 7] = Sbuf[n0 * 8 + tid];
    __syncthreads();

    {   // build h tile: thread = column hc
        const int c = tid, h = c >> 6;
        const float wl0 = W1l[c], wl1 = W1l[256 + c];
        const float bs = b1l[c] + bias1[c];
        #pragma unroll 4
        for (int n = 0; n < 16; ++n) {
            float g = fmaf(wl0, sS[n][h], fmaf(wl1, sS[n][4 + h], bs));
            hs[n][c] = g > 0.0f ? g : expm1f(g);
        }
    }
    __syncthreads();

    const int c = tid & 63, q = tid >> 6;
    float accL[4] = {0, 0, 0, 0}, accR[4] = {0, 0, 0, 0};
    for (int k = 0; k < 256; k += 4) {
        const float4 wl = *(const float4*)&W2lt[c * 256 + k];
        const float4 wr = *(const float4*)&W2rt[c * 256 + k];
        #pragma unroll
        for (int j = 0; j < 4; ++j) {
            const float4 hv = *(const float4*)&hs[q * 4 + j][k];
            accL[j] = fmaf(hv.x, wl.x, fmaf(hv.y, wl.y, fmaf(hv.z, wl.z, fmaf(hv.w, wl.w, accL[j]))));
            accR[j] = fmaf(hv.x, wr.x, fmaf(hv.y, wr.y, fmaf(hv.z, wr.z, fmaf(hv.w, wr.w, accR[j]))));
        }
    }
    const float bl = b2l[c], br = b2r[c];
    #pragma unroll
    for (int j = 0; j < 4; ++j) {
        int n = n0 + q * 4 + j;
        xl2[n * 64 + c] = accL[j] + bl;
        xr2[n * 64 + c] = accR[j] + br;
    }
}

// ---------------- Layer 2: single-pass online-softmax GATv2 (H=1, C=64) ----------------

__global__ __launch_bounds__(256) void l2_fused_kernel(
    const float* __restrict__ xl2, const float* __restrict__ xr2,
    const int* __restrict__ offs, const int* __restrict__ e_src,
    const float* __restrict__ e_ea,
    const float* __restrict__ W2e, const float* __restrict__ att2,
    const float* __restrict__ bias2, float* __restrict__ out2) {
    __shared__ float sWe[128], satt[64], sb[64];
    int tid = threadIdx.x;
    if (tid < 128) sWe[tid] = W2e[tid];
    if (tid < 64) { satt[tid] = att2[tid]; sb[tid] = bias2[tid]; }
    __syncthreads();

    const int l = tid & 63;
    const int n = blockIdx.x * 4 + (tid >> 6);

    const float xr = xr2[n * C2 + l];
    const float we0 = sWe[l], we1 = sWe[64 + l], at = satt[l];
    int beg = offs[n], end = offs[n + 1];

    float amax = -1e30f, den = 0.0f, acc = 0.0f;
    for (int e = beg; e < end; ++e) {
        int s = e_src[e];
        const float2 ae = *(const float2*)&e_ea[2 * e];
        float xl = xl2[s * C2 + l];
        float t = xl + xr + fmaf(ae.x, we0, ae.y * we1);
        t = t > 0.0f ? t : 0.2f * t;
        float p = t * at;
        #pragma unroll
        for (int off = 32; off; off >>= 1) p += __shfl_xor(p, off);
        float mnew = fmaxf(amax, p);
        float sc = __expf(amax - mnew);
        float w = __expf(p - mnew);
        den = fmaf(den, sc, w);
        acc = fmaf(acc, sc, w * xl);
        amax = mnew;
    }
    out2[n * C2 + l] = acc / (den + 1e-16f) + sb[l];
}

// ---------------- Mean pool ----------------

__global__ __launch_bounds__(256) void pool_kernel(const float* __restrict__ out2,
                                                   float* __restrict__ d_out) {
    __shared__ float s[256];
    int tid = threadIdx.x;
    float local = 0.0f;
    for (long long i = (long long)blockIdx.x * 256 + tid; i < (long long)N_NODES * C2;
         i += (long long)gridDim.x * 256)
        local += out2[i];
    s[tid] = local;
    __syncthreads();
    if (tid < 64) {
        float v = s[tid] + s[tid + 64] + s[tid + 128] + s[tid + 192];
        atomicAdd(&d_out[tid], v * (1.0f / N_NODES));
    }
}

// ---------------- Host launch ----------------

extern "C" void kernel_launch(void* const* d_in, const int* in_sizes, int n_in,
                              void* d_out, int out_size, void* d_ws, size_t ws_size,
                              hipStream_t stream) {
    const float* x     = (const float*)d_in[0];
    const float* eattr = (const float*)d_in[1];
    const float* W1l   = (const float*)d_in[2];
    const float* b1l   = (const float*)d_in[3];
    const float* W1r   = (const float*)d_in[4];
    const float* b1r   = (const float*)d_in[5];
    const float* W1e   = (const float*)d_in[6];
    const float* att1  = (const float*)d_in[7];
    const float* bias1 = (const float*)d_in[8];
    const float* W2l   = (const float*)d_in[9];
    const float* b2l   = (const float*)d_in[10];
    const float* W2r   = (const float*)d_in[11];
    const float* b2r   = (const float*)d_in[12];
    const float* W2e   = (const float*)d_in[13];
    const float* att2  = (const float*)d_in[14];
    const float* bias2 = (const float*)d_in[15];
    const int*   ei    = (const int*)d_in[16];
    float* out = (float*)d_out;

    // workspace layout (256B aligned blocks)
    char* p = (char*)d_ws;
    auto alloc = [&](size_t bytes) -> void* {
        void* r = (void*)p;
        p += (bytes + 255) & ~(size_t)255;
        return r;
    };
    int*   deg    = (int*)alloc(N_NODES * 4);
    int*   cnt    = (int*)alloc(N_NODES * 4);
    int*   offs   = (int*)alloc((N_NODES + 1) * 4);
    float* lsum   = (float*)alloc(N_NODES * 2 * 4);
    int*   bsum   = (int*)alloc(256 * 4);
    int*   e_src  = (int*)alloc(E_AUG * 4);
    int*   e_dst  = (int*)alloc(E_AUG * 4);
    float* e_ea   = (float*)alloc((size_t)E_AUG * 2 * 4);
    float* alpha1 = (float*)alloc((size_t)E_AUG * 4 * 4);
    float* Sbuf   = (float*)alloc((size_t)N_NODES * 8 * 4);
    float* Wpack  = (float*)alloc(256 * 8 * 4);
    float* W2lt   = (float*)alloc(256 * 64 * 4);
    float* W2rt   = (float*)alloc(256 * 64 * 4);
    float* xl2    = (float*)alloc((size_t)N_NODES * C2 * 4);
    float* xr2    = (float*)alloc((size_t)N_NODES * C2 * 4);
    float* out2   = (float*)alloc((size_t)N_NODES * C2 * 4);

    hipMemsetAsync(deg, 0, N_NODES * 4, stream);
    hipMemsetAsync(cnt, 0, N_NODES * 4, stream);
    hipMemsetAsync(lsum, 0, N_NODES * 2 * 4, stream);
    hipMemsetAsync(d_out, 0, 64 * 4, stream);

    pack_kernel<<<64, 256, 0, stream>>>(W1l, b1l, W1r, b1r, W1e, att1, W2l, W2r,
                                        Wpack, W2lt, W2rt);

    deg_loop_kernel<<<(N_EDGES + 255) / 256, 256, 0, stream>>>(ei, eattr, deg, lsum);
    int nb = (N_NODES + 255) / 256;   // 196
    scan1_kernel<<<nb, 256, 0, stream>>>(deg, offs, bsum);
    scan2_kernel<<<1, 256, 0, stream>>>(bsum, nb);
    scan3_kernel<<<nb, 256, 0, stream>>>(offs, bsum);
    scatter_kernel<<<(E_AUG + 255) / 256, 256, 0, stream>>>(ei, eattr, deg, lsum, offs, cnt,
                                                            e_src, e_dst, e_ea);

    l1_alpha_kernel<<<(E_AUG / 4 + 255) / 256, 256, 0, stream>>>(x, e_src, e_dst, e_ea,
                                                                 Wpack, alpha1);

    l1_softmax_kernel<<<(N_NODES + 255) / 256, 256, 0, stream>>>(x, offs, e_src, alpha1, Sbuf);

    l1out_gemm_kernel<<<N_NODES / 16, 256, 0, stream>>>(Sbuf, W1l, b1l, bias1,
                                                        W2lt, b2l, W2rt, b2r, xl2, xr2);

    l2_fused_kernel<<<N_NODES / 4, 256, 0, stream>>>(xl2, xr2, offs, e_src, e_ea,
                                                     W2e, att2, bias2, out2);

    pool_kernel<<<256, 256, 0, stream>>>(out2, out);
}

// Round 3
// 362.512 us; speedup vs baseline: 1.5031x; 1.3346x over previous
//
#include <hip/hip_runtime.h>
#include <hip/hip_bf16.h>

#define N_NODES 50000
#define N_EDGES 500000
#define E_AUG   (N_EDGES + N_NODES)   // 550000 (divisible by 4)
#define NH1 4
#define HID 64
#define C1  256                        // NH1*HID
#define C2  64

// ---------------- weight packing ----------------
// Wpack[c][h][8] = {Wl0, Wl1, Wr0, Wr1, We0, We1, b1l+b1r, att1} for column hc=h*64+c

__global__ void pack_kernel(const float* __restrict__ W1l, const float* __restrict__ b1l,
                            const float* __restrict__ W1r, const float* __restrict__ b1r,
                            const float* __restrict__ W1e, const float* __restrict__ att1,
                            float* __restrict__ Wpack) {
    int t = threadIdx.x;
    if (t < 256) {
        int h = t >> 6, c = t & 63, hc = t;
        float* wp = &Wpack[(c * 4 + h) * 8];
        wp[0] = W1l[hc];       wp[1] = W1l[256 + hc];
        wp[2] = W1r[hc];       wp[3] = W1r[256 + hc];
        wp[4] = W1e[hc];       wp[5] = W1e[256 + hc];
        wp[6] = b1l[hc] + b1r[hc];
        wp[7] = att1[hc];
    }
}

// ---------------- CSR build ----------------

__global__ void deg_loop_kernel(const int* __restrict__ ei, const float* __restrict__ ea,
                                int* __restrict__ deg, float* __restrict__ lsum) {
    int e = blockIdx.x * 256 + threadIdx.x;
    if (e >= N_EDGES) return;
    int d = ei[N_EDGES + e];
    atomicAdd(&deg[d], 1);
    atomicAdd(&lsum[2 * d + 0], ea[2 * e + 0]);
    atomicAdd(&lsum[2 * d + 1], ea[2 * e + 1]);
}

__global__ void scan1_kernel(const int* __restrict__ deg, int* __restrict__ offs,
                             int* __restrict__ bsum) {
    __shared__ int s[256];
    int tid = threadIdx.x;
    int i = blockIdx.x * 256 + tid;
    int v = (i < N_NODES) ? (deg[i] + 1) : 0;   // +1 self loop
    s[tid] = v;
    __syncthreads();
    for (int off = 1; off < 256; off <<= 1) {
        int t = (tid >= off) ? s[tid - off] : 0;
        __syncthreads();
        s[tid] += t;
        __syncthreads();
    }
    if (i < N_NODES) offs[i + 1] = s[tid];
    if (tid == 255) bsum[blockIdx.x] = s[255];
}

__global__ void scan2_kernel(int* __restrict__ bsum, int nb) {
    __shared__ int s[256];
    int tid = threadIdx.x;
    int v = (tid < nb) ? bsum[tid] : 0;
    s[tid] = v;
    __syncthreads();
    for (int off = 1; off < 256; off <<= 1) {
        int t = (tid >= off) ? s[tid - off] : 0;
        __syncthreads();
        s[tid] += t;
        __syncthreads();
    }
    if (tid < nb) bsum[tid] = s[tid] - v;   // exclusive
}

__global__ void scan3_kernel(int* __restrict__ offs, const int* __restrict__ bsum) {
    int i = blockIdx.x * 256 + threadIdx.x;
    if (i < N_NODES) offs[i + 1] += bsum[i >> 8];
    if (i == 0) offs[0] = 0;
}

__global__ void scatter_kernel(const int* __restrict__ ei, const float* __restrict__ ea,
                               const int* __restrict__ deg, const float* __restrict__ lsum,
                               const int* __restrict__ offs, int* __restrict__ cnt,
                               int* __restrict__ e_src, int* __restrict__ e_dst,
                               float* __restrict__ e_ea) {
    int e = blockIdx.x * 256 + threadIdx.x;
    if (e >= E_AUG) return;
    int s, d; float a0, a1;
    if (e < N_EDGES) {
        s = ei[e]; d = ei[N_EDGES + e];
        a0 = ea[2 * e + 0]; a1 = ea[2 * e + 1];
    } else {
        int n = e - N_EDGES;
        s = n; d = n;
        float dg = (float)max(deg[n], 1);
        a0 = lsum[2 * n + 0] / dg;
        a1 = lsum[2 * n + 1] / dg;
    }
    int pos = offs[d] + atomicAdd(&cnt[d], 1);
    e_src[pos] = s;
    e_dst[pos] = d;
    e_ea[2 * pos + 0] = a0;
    e_ea[2 * pos + 1] = a1;
}

// ---------------- Layer 1 alpha: edge-parallel, 4 edges/thread ----------------

__global__ __launch_bounds__(256) void l1_alpha_kernel(
    const float* __restrict__ x, const int* __restrict__ e_src,
    const int* __restrict__ e_dst, const float* __restrict__ e_ea,
    const float* __restrict__ Wpack, float* __restrict__ alpha1) {
    __shared__ float sWp[2048];
    const int tid = threadIdx.x;
    for (int i = tid; i < 2048; i += 256) sWp[i] = Wpack[i];
    __syncthreads();

    const int e0 = (blockIdx.x * 256 + tid) * 4;
    if (e0 >= E_AUG) return;   // E_AUG % 4 == 0 -> full quads only

    const int4 s4 = *(const int4*)&e_src[e0];
    const int4 d4 = *(const int4*)&e_dst[e0];
    const float4 ea0 = *(const float4*)&e_ea[2 * e0];
    const float4 ea1 = *(const float4*)&e_ea[2 * e0 + 4];

    float u0[4], u1[4], u2[4], u3[4], u4[4], u5[4];
    {
        const int ss[4] = {s4.x, s4.y, s4.z, s4.w};
        const int dd[4] = {d4.x, d4.y, d4.z, d4.w};
        const float ae[8] = {ea0.x, ea0.y, ea0.z, ea0.w, ea1.x, ea1.y, ea1.z, ea1.w};
        #pragma unroll
        for (int j = 0; j < 4; ++j) {
            float2 xs = *(const float2*)&x[2 * ss[j]];
            float2 xd = *(const float2*)&x[2 * dd[j]];
            u0[j] = xs.x; u1[j] = xs.y; u2[j] = xd.x; u3[j] = xd.y;
            u4[j] = ae[2 * j]; u5[j] = ae[2 * j + 1];
        }
    }

    float p[4][4];
    #pragma unroll
    for (int h = 0; h < 4; ++h)
        #pragma unroll
        for (int j = 0; j < 4; ++j) p[h][j] = 0.0f;

    for (int c = 0; c < 64; ++c) {
        const float* wp = &sWp[c * 32];
        #pragma unroll
        for (int h = 0; h < 4; ++h) {
            const float4 wa = *(const float4*)&wp[h * 8];
            const float4 wb = *(const float4*)&wp[h * 8 + 4];
            #pragma unroll
            for (int j = 0; j < 4; ++j) {
                float t = fmaf(u0[j], wa.x,
                          fmaf(u1[j], wa.y,
                          fmaf(u2[j], wa.z,
                          fmaf(u3[j], wa.w,
                          fmaf(u4[j], wb.x,
                          fmaf(u5[j], wb.y, wb.z))))));
                t = t > 0.0f ? t : 0.2f * t;
                p[h][j] = fmaf(t, wb.w, p[h][j]);
            }
        }
    }

    #pragma unroll
    for (int j = 0; j < 4; ++j) {
        float4 v = make_float4(p[0][j], p[1][j], p[2][j], p[3][j]);
        *(float4*)&alpha1[4 * (e0 + j)] = v;
    }
}

// ---------------- Layer 1: online softmax + rank-2 weighted sums ----------------
// Sbuf[n][0..3] = sum_e w_eh * x[s_e].x ; Sbuf[n][4..7] = sum_e w_eh * x[s_e].y

__global__ __launch_bounds__(256) void l1_softmax_kernel(
    const float* __restrict__ x, const int* __restrict__ offs,
    const int* __restrict__ e_src, const float* __restrict__ alpha1,
    float* __restrict__ Sbuf) {
    int n = blockIdx.x * 256 + threadIdx.x;
    if (n >= N_NODES) return;
    int beg = offs[n], end = offs[n + 1];

    float amax[4] = {-1e30f, -1e30f, -1e30f, -1e30f};
    float den[4] = {0, 0, 0, 0}, s1[4] = {0, 0, 0, 0}, s2[4] = {0, 0, 0, 0};
    for (int e = beg; e < end; ++e) {
        const float4 lg = *(const float4*)&alpha1[4 * e];
        float lgv[4] = {lg.x, lg.y, lg.z, lg.w};
        int s = e_src[e];
        float2 xs = *(const float2*)&x[2 * s];
        #pragma unroll
        for (int h = 0; h < 4; ++h) {
            float m = fmaxf(amax[h], lgv[h]);
            float sc = __expf(amax[h] - m);
            float w = __expf(lgv[h] - m);
            den[h] = fmaf(den[h], sc, w);
            s1[h] = fmaf(s1[h], sc, w * xs.x);
            s2[h] = fmaf(s2[h], sc, w * xs.y);
            amax[h] = m;
        }
    }
    #pragma unroll
    for (int h = 0; h < 4; ++h) {
        float inv = 1.0f / (den[h] + 1e-16f);
        Sbuf[n * 8 + h] = s1[h] * inv;
        Sbuf[n * 8 + 4 + h] = s2[h] * inv;
    }
}

// ---------------- Layer 1 output tile (in LDS) + layer 2 projections ----------------
// h[n,hc] = elu(Wl0[hc]*S1[n,h] + Wl1[hc]*S2[n,h] + b1l[hc] + bias1[hc])  (never hits HBM)
// xl2 = h@W2l + b2l ; xr2 = h@W2r + b2r   (W2 in original [256,64] layout -> coalesced)

__global__ __launch_bounds__(256) void l1out_gemm_kernel(
    const float* __restrict__ Sbuf,
    const float* __restrict__ W1l, const float* __restrict__ b1l,
    const float* __restrict__ bias1,
    const float* __restrict__ W2l, const float* __restrict__ b2l,
    const float* __restrict__ W2r, const float* __restrict__ b2r,
    float* __restrict__ xl2, float* __restrict__ xr2) {
    __shared__ float sS[32][8];
    __shared__ float hs[32][256];
    const int tid = threadIdx.x;
    const int n0 = blockIdx.x * 32;
    {
        int idx = n0 * 8 + tid;              // 32 nodes * 8 floats
        sS[tid >> 3][tid & 7] = (idx < N_NODES * 8) ? Sbuf[idx] : 0.0f;
    }
    __syncthreads();

    {   // build h tile: thread = column hc for all 32 nodes
        const int c = tid, h = c >> 6;
        const float wl0 = W1l[c], wl1 = W1l[256 + c];
        const float bs = b1l[c] + bias1[c];
        #pragma unroll 4
        for (int n = 0; n < 32; ++n) {
            float g = fmaf(wl0, sS[n][h], fmaf(wl1, sS[n][4 + h], bs));
            hs[n][c] = g > 0.0f ? g : expm1f(g);
        }
    }
    __syncthreads();

    const int c = tid & 63, q = tid >> 6;
    const float* WL = &W2l[c];
    const float* WR = &W2r[c];
    float accL[8] = {0, 0, 0, 0, 0, 0, 0, 0};
    float accR[8] = {0, 0, 0, 0, 0, 0, 0, 0};
    for (int k = 0; k < 256; k += 4) {
        const float wl0 = WL[(k + 0) * 64], wl1 = WL[(k + 1) * 64],
                    wl2 = WL[(k + 2) * 64], wl3 = WL[(k + 3) * 64];
        const float wr0 = WR[(k + 0) * 64], wr1 = WR[(k + 1) * 64],
                    wr2 = WR[(k + 2) * 64], wr3 = WR[(k + 3) * 64];
        #pragma unroll
        for (int j = 0; j < 8; ++j) {
            const float4 hv = *(const float4*)&hs[q * 8 + j][k];
            accL[j] = fmaf(hv.x, wl0, fmaf(hv.y, wl1, fmaf(hv.z, wl2, fmaf(hv.w, wl3, accL[j]))));
            accR[j] = fmaf(hv.x, wr0, fmaf(hv.y, wr1, fmaf(hv.z, wr2, fmaf(hv.w, wr3, accR[j]))));
        }
    }
    const float bl = b2l[c], br = b2r[c];
    #pragma unroll
    for (int j = 0; j < 8; ++j) {
        int n = n0 + q * 8 + j;
        if (n < N_NODES) {
            xl2[n * 64 + c] = accL[j] + bl;
            xr2[n * 64 + c] = accR[j] + br;
        }
    }
}

// ---------------- Layer 2: single-pass online-softmax GATv2 (H=1, C=64) ----------------

__global__ __launch_bounds__(256) void l2_fused_kernel(
    const float* __restrict__ xl2, const float* __restrict__ xr2,
    const int* __restrict__ offs, const int* __restrict__ e_src,
    const float* __restrict__ e_ea,
    const float* __restrict__ W2e, const float* __restrict__ att2,
    const float* __restrict__ bias2, float* __restrict__ out2) {
    __shared__ float sWe[128], satt[64], sb[64];
    int tid = threadIdx.x;
    if (tid < 128) sWe[tid] = W2e[tid];
    if (tid < 64) { satt[tid] = att2[tid]; sb[tid] = bias2[tid]; }
    __syncthreads();

    const int l = tid & 63;
    const int n = blockIdx.x * 4 + (tid >> 6);

    const float xr = xr2[n * C2 + l];
    const float we0 = sWe[l], we1 = sWe[64 + l], at = satt[l];
    int beg = offs[n], end = offs[n + 1];

    float amax = -1e30f, den = 0.0f, acc = 0.0f;
    for (int e = beg; e < end; ++e) {
        int s = e_src[e];
        const float2 ae = *(const float2*)&e_ea[2 * e];
        float xl = xl2[s * C2 + l];
        float t = xl + xr + fmaf(ae.x, we0, ae.y * we1);
        t = t > 0.0f ? t : 0.2f * t;
        float p = t * at;
        #pragma unroll
        for (int off = 32; off; off >>= 1) p += __shfl_xor(p, off);
        float mnew = fmaxf(amax, p);
        float sc = __expf(amax - mnew);
        float w = __expf(p - mnew);
        den = fmaf(den, sc, w);
        acc = fmaf(acc, sc, w * xl);
        amax = mnew;
    }
    out2[n * C2 + l] = acc / (den + 1e-16f) + sb[l];
}

// ---------------- Mean pool ----------------

__global__ __launch_bounds__(256) void pool_kernel(const float* __restrict__ out2,
                                                   float* __restrict__ d_out) {
    __shared__ float s[256];
    int tid = threadIdx.x;
    float local = 0.0f;
    for (long long i = (long long)blockIdx.x * 256 + tid; i < (long long)N_NODES * C2;
         i += (long long)gridDim.x * 256)
        local += out2[i];
    s[tid] = local;
    __syncthreads();
    if (tid < 64) {
        float v = s[tid] + s[tid + 64] + s[tid + 128] + s[tid + 192];
        atomicAdd(&d_out[tid], v * (1.0f / N_NODES));
    }
}

// ---------------- Host launch ----------------

extern "C" void kernel_launch(void* const* d_in, const int* in_sizes, int n_in,
                              void* d_out, int out_size, void* d_ws, size_t ws_size,
                              hipStream_t stream) {
    const float* x     = (const float*)d_in[0];
    const float* eattr = (const float*)d_in[1];
    const float* W1l   = (const float*)d_in[2];
    const float* b1l   = (const float*)d_in[3];
    const float* W1r   = (const float*)d_in[4];
    const float* b1r   = (const float*)d_in[5];
    const float* W1e   = (const float*)d_in[6];
    const float* att1  = (const float*)d_in[7];
    const float* bias1 = (const float*)d_in[8];
    const float* W2l   = (const float*)d_in[9];
    const float* b2l   = (const float*)d_in[10];
    const float* W2r   = (const float*)d_in[11];
    const float* b2r   = (const float*)d_in[12];
    const float* W2e   = (const float*)d_in[13];
    const float* att2  = (const float*)d_in[14];
    const float* bias2 = (const float*)d_in[15];
    const int*   ei    = (const int*)d_in[16];
    float* out = (float*)d_out;

    // workspace layout (256B aligned blocks)
    char* p = (char*)d_ws;
    auto alloc = [&](size_t bytes) -> void* {
        void* r = (void*)p;
        p += (bytes + 255) & ~(size_t)255;
        return r;
    };
    int*   deg    = (int*)alloc(N_NODES * 4);
    int*   cnt    = (int*)alloc(N_NODES * 4);
    int*   offs   = (int*)alloc((N_NODES + 1) * 4);
    float* lsum   = (float*)alloc(N_NODES * 2 * 4);
    int*   bsum   = (int*)alloc(256 * 4);
    int*   e_src  = (int*)alloc(E_AUG * 4);
    int*   e_dst  = (int*)alloc(E_AUG * 4);
    float* e_ea   = (float*)alloc((size_t)E_AUG * 2 * 4);
    float* alpha1 = (float*)alloc((size_t)E_AUG * 4 * 4);
    float* Sbuf   = (float*)alloc((size_t)N_NODES * 8 * 4);
    float* Wpack  = (float*)alloc(256 * 8 * 4);
    float* xl2    = (float*)alloc((size_t)N_NODES * C2 * 4);
    float* xr2    = (float*)alloc((size_t)N_NODES * C2 * 4);
    float* out2   = (float*)alloc((size_t)N_NODES * C2 * 4);

    hipMemsetAsync(deg, 0, N_NODES * 4, stream);
    hipMemsetAsync(cnt, 0, N_NODES * 4, stream);
    hipMemsetAsync(lsum, 0, N_NODES * 2 * 4, stream);
    hipMemsetAsync(d_out, 0, 64 * 4, stream);

    pack_kernel<<<1, 256, 0, stream>>>(W1l, b1l, W1r, b1r, W1e, att1, Wpack);

    deg_loop_kernel<<<(N_EDGES + 255) / 256, 256, 0, stream>>>(ei, eattr, deg, lsum);
    int nb = (N_NODES + 255) / 256;   // 196
    scan1_kernel<<<nb, 256, 0, stream>>>(deg, offs, bsum);
    scan2_kernel<<<1, 256, 0, stream>>>(bsum, nb);
    scan3_kernel<<<nb, 256, 0, stream>>>(offs, bsum);
    scatter_kernel<<<(E_AUG + 255) / 256, 256, 0, stream>>>(ei, eattr, deg, lsum, offs, cnt,
                                                            e_src, e_dst, e_ea);

    l1_alpha_kernel<<<(E_AUG / 4 + 255) / 256, 256, 0, stream>>>(x, e_src, e_dst, e_ea,
                                                                 Wpack, alpha1);

    l1_softmax_kernel<<<(N_NODES + 255) / 256, 256, 0, stream>>>(x, offs, e_src, alpha1, Sbuf);

    l1out_gemm_kernel<<<(N_NODES + 31) / 32, 256, 0, stream>>>(Sbuf, W1l, b1l, bias1,
                                                               W2l, b2l, W2r, b2r, xl2, xr2);

    l2_fused_kernel<<<N_NODES / 4, 256, 0, stream>>>(xl2, xr2, offs, e_src, e_ea,
                                                     W2e, att2, bias2, out2);

    pool_kernel<<<256, 256, 0, stream>>>(out2, out);
}